// Round 4
// baseline (533.981 us; speedup 1.0000x reference)
//
#include <hip/hip_runtime.h>

// Problem constants (match reference.py)
#define B_ 2
#define L_ 1024
#define M_ 8
#define N_ 16
#define C_ 16
#define H_ 64
#define W_ 64

#define NVOTE (M_ * N_)        // 128 votes per (b,l)
#define PLANE (H_ * W_)        // 4096 floats per channel plane (16 KiB)

// native clang vector (HIP's float4 is a class -> rejected by
// __builtin_nontemporal_store)
typedef float vfloat4 __attribute__((ext_vector_type(4)));

// d_ws layout:
//   [0, 1 MiB):  ws_bin  int32  [B*L][NVOTE]      flattened bin, -1 = invalid
//   [1 MiB, +16 MiB): ws_w float [B*L][C][NVOTE]  weights transposed per channel

// ---------------------------------------------------------------------------
// Pass 1: resolve the gather chain ONCE per vote; write compact coalesced
// records. This removes the 3-deep dependent-load chain (idxs_src ->
// voxels/idxs_dst -> voxels_dst -> feats, each a likely HBM miss while the
// streaming pass evicts L2) from the store-bound pass.
// ---------------------------------------------------------------------------
__global__ __launch_bounds__(128) void vote_precompute(
    const float* __restrict__ feats,       // [B,L,N,C] f32
    const int*   __restrict__ voxels_src,  // [B,L,2]   i32
    const int*   __restrict__ voxels_dst,  // [B,L,2]   i32
    const int*   __restrict__ idxs_src,    // [B,L,M]   i32
    const int*   __restrict__ idxs_dst,    // [B,L,N]   i32
    int*         __restrict__ ws_bin,      // [B*L][NVOTE]
    float*       __restrict__ ws_w)        // [B*L][C][NVOTE]
{
    const int bl = blockIdx.x;             // 0 .. B*L-1
    const int b  = bl >> 10;               // L == 1024
    const int t  = threadIdx.x;            // vote id 0..127
    const int m  = t >> 4;
    const int n  = t & (N_ - 1);

    int  s    = idxs_src[bl * M_ + m];
    int  base = b * L_ + s;
    int2 vs   = ((const int2*)voxels_src)[base];
    int  dd   = idxs_dst[base * N_ + n];
    int2 vd   = ((const int2*)voxels_dst)[b * L_ + dd];

    // voxels are ints: floor(float diff) == int diff exactly
    int by = vd.x - vs.x + H_ / 2;
    int bx = vd.y - vs.y + W_ / 2;
    bool valid = (by >= 0) & (by < H_) & (bx >= 0) & (bx < W_);
    ws_bin[bl * NVOTE + t] = valid ? (by * W_ + bx) : -1;

    // all 16 channel weights for this vote: feats[b, s, n, :] = 64 B contiguous
    const vfloat4* f4 = (const vfloat4*)(feats + ((size_t)base * N_ + n) * C_);
    vfloat4 w0 = f4[0], w1 = f4[1], w2 = f4[2], w3 = f4[3];
    float wr[C_] = { w0.x, w0.y, w0.z, w0.w,  w1.x, w1.y, w1.z, w1.w,
                     w2.x, w2.y, w2.z, w2.w,  w3.x, w3.y, w3.z, w3.w };

    // transpose-on-store: for each c the 128 lanes write 128 consecutive
    // floats -> 16 fully coalesced 512 B stores, no LDS needed
    float* wb = ws_w + (size_t)bl * (C_ * NVOTE) + t;
    #pragma unroll
    for (int c = 0; c < C_; ++c)
        wb[c * NVOTE] = wr[c];
}

// ---------------------------------------------------------------------------
// Pass 2: one block per (b,l,c). Prologue = 2 independent coalesced loads.
// Build the 16 KiB plane in LDS, store exactly once with nontemporal float4
// (no barrier after the store; fire-and-forget at endpgm).
// ---------------------------------------------------------------------------
__global__ __launch_bounds__(256) void hough_plane_kernel(
    const int*   __restrict__ ws_bin,      // [B*L][NVOTE]
    const float* __restrict__ ws_w,        // [B*L][C][NVOTE]
    float*       __restrict__ out)         // [B,L,C,H,W] f32
{
    const int gb  = blockIdx.x;            // = (bl*C + c), matches out layout
    const int bl  = gb >> 4;
    const int c   = gb & (C_ - 1);
    const int tid = threadIdx.x;           // 0..255

    __shared__ float s_plane[PLANE];

    // ---- load this plane's votes: flat, independent, coalesced ------------
    int   bin = -1;
    float w   = 0.f;
    if (tid < NVOTE) {
        bin = ws_bin[bl * NVOTE + tid];                       // 512 B, shared by 16 c-blocks
        w   = ws_w[((size_t)bl * C_ + c) * NVOTE + tid];      // 512 B
    }

    // ---- zero the plane (overlaps the loads above) ------------------------
    vfloat4* p4 = (vfloat4*)s_plane;
    vfloat4  z  = {0.f, 0.f, 0.f, 0.f};
    #pragma unroll
    for (int i = 0; i < PLANE / 4 / 256; ++i)
        p4[i * 256 + tid] = z;
    __syncthreads();

    // ---- scatter votes (LDS atomics absorb bin collisions) ----------------
    if (bin >= 0) atomicAdd(&s_plane[bin], w);
    __syncthreads();

    // ---- store the plane: coalesced nontemporal float4, written once ------
    vfloat4* o4 = (vfloat4*)(out + (size_t)gb * PLANE);
    #pragma unroll
    for (int i = 0; i < PLANE / 4 / 256; ++i)
        __builtin_nontemporal_store(p4[i * 256 + tid], &o4[i * 256 + tid]);
}

extern "C" void kernel_launch(void* const* d_in, const int* in_sizes, int n_in,
                              void* d_out, int out_size, void* d_ws, size_t ws_size,
                              hipStream_t stream) {
    const float* feats      = (const float*)d_in[0];
    const int*   voxels_src = (const int*)d_in[1];
    const int*   voxels_dst = (const int*)d_in[2];
    const int*   idxs_src   = (const int*)d_in[3];
    const int*   idxs_dst   = (const int*)d_in[4];
    float*       out        = (float*)d_out;

    int*   ws_bin = (int*)d_ws;
    float* ws_w   = (float*)((char*)d_ws + (1 << 20));   // 1 MiB offset

    vote_precompute<<<B_ * L_, 128, 0, stream>>>(
        feats, voxels_src, voxels_dst, idxs_src, idxs_dst, ws_bin, ws_w);

    hough_plane_kernel<<<B_ * L_ * C_, 256, 0, stream>>>(
        ws_bin, ws_w, out);
}